// Round 6
// baseline (568.830 us; speedup 1.0000x reference)
//
#include <hip/hip_runtime.h>
#include <math.h>

// RNN_197568496340: 6-layer ReLU RNN (T=1024,B=2048,IN=2,H=20) + FC(20->2) + log_softmax.
//
// R6 = R5 + register-allocator pinning.
//  - R5 evidence: VGPR_Count=64 with ~195 VALU insts/wave/step (~85 over the
//    80-FMA + misc ideal) -> the 80 weight floats/lane are parked in the
//    unified-file AGPR side (or scratch), costing a move per use per step.
//  - Fix: amdgpu_waves_per_eu(2,2) pins the occupancy target to what the grid
//    (2048 blocks = 8 waves/CU = 2/SIMD) delivers anyway -> 256-reg budget ->
//    weights live in arch VGPRs.
//  - Also removed the per-step sched_barrier(0): DS ops are in-order per wave
//    and the compiler sees the LDS aliasing, so cross-step overlap (next
//    step's ds_reads under this step's FMA tail) is legal and now allowed.
//  - Everything else identical to R5 (2048 single-wave persistent blocks,
//    diagonal layer schedule, zero barriers, staged uniform weight init).

#define TT 1024
#define BB 2048
#define HH 20
#define LL 6
#define SLOTW 40
#define BUFW  (8 * SLOTW)       // 320 words/parity: slots 0=x,1..6=layer outs,7=zeros
#define NSTEPS (TT + LL)        // 1030 (even)

// ws layout (floats)
#define WS_WI   0               // padded Wih: [6][20][20] (layer0 = Wih0 zero-padded)
#define WS_BIAS 2400            // BiasTab: [61][2]  (role 60 = fcb)

__global__ void stage_ws(const float* __restrict__ Wih0,
                         const float* __restrict__ Wih,
                         const float* __restrict__ bih,
                         const float* __restrict__ bhh,
                         const float* __restrict__ fcb,
                         float* __restrict__ ws) {
    const int i = threadIdx.x + blockIdx.x * blockDim.x;
    if (i < 2400) {
        const int l = i / 400, r = i % 400, j = r / 20, k = r % 20;
        float v;
        if (l == 0) v = (k < 2) ? Wih0[j * 2 + k] : 0.f;
        else        v = Wih[(l - 1) * 400 + r];
        ws[WS_WI + i] = v;
    }
    if (i < 122) {
        const int role = i >> 1, c = i & 1;
        float v;
        if (role < 60) {
            const int l = role / 10, j = 2 * (role % 10) + c;
            v = bih[l * HH + j] + bhh[l * HH + j];
        } else {
            v = fcb[c];
        }
        ws[WS_BIAS + i] = v;
    }
}

__global__ __launch_bounds__(64)
__attribute__((amdgpu_waves_per_eu(2, 2)))
void rnn_fused(const float* __restrict__ x,      // [1024][2048][2]
               const float* __restrict__ Whh,    // [6][20][20]
               const float* __restrict__ fcw,    // [2][20]
               const float* __restrict__ ws,     // staged WI_pad + BiasTab
               float* __restrict__ out)          // [1024][2048][2]
{
    __shared__ __align__(16) float As[2 * BUFW];   // 2560 B

    const int lane = threadIdx.x;
    // XCD swizzle: consecutive b on the same XCD -> L2 write combining
    const int b = ((blockIdx.x & 7) << 8) | (blockIdx.x >> 3);

    const int  role = (lane < 60) ? lane : 60;
    const int  l    = role / 10;            // 0..6 (6 = head pseudo-layer)
    const int  j    = 2 * (role % 10);      // 0 for head
    const bool head = (role == 60);

    // ---- branch-free uniform weight init (pointers differ, code identical) ----
    const float4* pwh = (const float4*)(head ? Whh : (Whh + (l * HH + j) * HH));
    const float4* pwi = (const float4*)(head ? fcw : (ws + WS_WI + (l * HH + j) * HH));
    const float2  bt  = *(const float2*)(ws + WS_BIAS + 2 * role);

    float4 whA[5], whB[5], wiA[5], wiB[5];
#pragma unroll
    for (int q = 0; q < 5; ++q) {
        whA[q] = pwh[q];
        whB[q] = pwh[5 + q];
        wiA[q] = pwi[q];
        wiB[q] = pwi[5 + q];
    }

    // ---- LDS init: everything zero (h(-1)=0, zero-slot stays zero forever) ----
    for (int i = lane; i < 2 * BUFW; i += 64) As[i] = 0.f;

    // x staging: x[0] -> buf0 slot0; ring lanes 61..63 hold x[1..3]
    const float2* xp = (const float2*)x;
    float2 xh = make_float2(0.f, 0.f);
    if (lane == 61) *(float2*)&As[0] = xp[b];
    if (lane >= 61) xh = xp[(size_t)(lane - 60) * BB + b];

    // per-lane LDS word offsets (uniform formula, head included)
    const int ioff = l * SLOTW;             // input slot (head: slot 6 = h5)
    const int hoff = (l + 1) * SLOTW;       // recurrent slot (head: slot 7 = zeros)
    float2* const op = (float2*)out;

    auto step = [&](int s, const float* rb, float* wb) {
        const float4* hp = (const float4*)(rb + hoff);
        const float4* ip = (const float4*)(rb + ioff);

        float ah0 = 0.f, ah1 = 0.f;
        float ai0 = bt.x, ai1 = bt.y;
#pragma unroll
        for (int q = 0; q < 5; ++q) {
            const float4 h4 = hp[q];
            const float4 i4 = ip[q];
            ah0 = fmaf(whA[q].x, h4.x, ah0); ah0 = fmaf(whA[q].y, h4.y, ah0);
            ah0 = fmaf(whA[q].z, h4.z, ah0); ah0 = fmaf(whA[q].w, h4.w, ah0);
            ah1 = fmaf(whB[q].x, h4.x, ah1); ah1 = fmaf(whB[q].y, h4.y, ah1);
            ah1 = fmaf(whB[q].z, h4.z, ah1); ah1 = fmaf(whB[q].w, h4.w, ah1);
            ai0 = fmaf(wiA[q].x, i4.x, ai0); ai0 = fmaf(wiA[q].y, i4.y, ai0);
            ai0 = fmaf(wiA[q].z, i4.z, ai0); ai0 = fmaf(wiA[q].w, i4.w, ai0);
            ai1 = fmaf(wiB[q].x, i4.x, ai1); ai1 = fmaf(wiB[q].y, i4.y, ai1);
            ai1 = fmaf(wiB[q].z, i4.z, ai1); ai1 = fmaf(wiB[q].w, i4.w, ai1);
        }
        const float a0 = ah0 + ai0;
        const float a1 = ah1 + ai1;

        if (role < 60) {
            if ((unsigned)(s - l) < TT) {                  // t in [0,1023]
                float2 r;
                r.x = fmaxf(a0, 0.f);
                r.y = fmaxf(a1, 0.f);
                *(float2*)(wb + hoff + j) = r;
            }
        } else if (lane == 60) {
            if (s >= LL) {
                const float mx  = fmaxf(a0, a1);
                const float lse = mx + __logf(__expf(a0 - mx) + __expf(a1 - mx));
                op[(size_t)(s - LL) * BB + b] = make_float2(a0 - lse, a1 - lse);
            }
        } else {
            // x ring: lane d = lane-61 acts when s % 3 == d; publishes x[s+1],
            // then prefetches x[s+4] (3 steps of latency slack)
            if (lane - 61 == s % 3) {
                if (s + 1 < TT) *(float2*)(wb + 0) = xh;
                int tl = s + 4; if (tl > TT - 1) tl = TT - 1;
                xh = xp[(size_t)tl * BB + b];
            }
        }
    };

    float* const buf0 = As;
    float* const buf1 = As + BUFW;
    for (int s = 0; s < NSTEPS; s += 2) {
        step(s,     buf0, buf1);
        step(s + 1, buf1, buf0);
    }
}

extern "C" void kernel_launch(void* const* d_in, const int* in_sizes, int n_in,
                              void* d_out, int out_size, void* d_ws, size_t ws_size,
                              hipStream_t stream) {
    const float* x    = (const float*)d_in[0];
    const float* Wih0 = (const float*)d_in[1];
    const float* Wih  = (const float*)d_in[2];
    const float* Whh  = (const float*)d_in[3];
    const float* bih  = (const float*)d_in[4];
    const float* bhh  = (const float*)d_in[5];
    const float* fcw  = (const float*)d_in[6];
    const float* fcb  = (const float*)d_in[7];
    float* out = (float*)d_out;
    float* ws  = (float*)d_ws;

    stage_ws<<<dim3(3), dim3(1024), 0, stream>>>(Wih0, Wih, bih, bhh, fcb, ws);
    rnn_fused<<<dim3(BB), dim3(64), 0, stream>>>(x, Whh, fcw, ws, out);
}